// Round 7
// baseline (2598.289 us; speedup 1.0000x reference)
//
#include <hip/hip_runtime.h>
#include <hip/hip_bf16.h>
#include <stdint.h>
#include <math.h>

typedef __bf16 bf16;
typedef __bf16 bf16x8 __attribute__((ext_vector_type(8)));
typedef float f32x4 __attribute__((ext_vector_type(4)));

// B=8, H=W=128, dim=256, mid=128. fp32 I/O; internal hi/lo bf16 pairs.
// conv = 3-term bf16 (WhAh + WhAl + WlAh) on 16x16x32 MFMA. A (weights)
// loaded global->reg per tap from a fragment-major repack
// [2*tap+s][ci_chunk][co][32ci]. B staged per chunk via global_load_lds w=16
// (linear LDS dest + inverse-swizzled global src). NEW: half-slab counted-vmcnt
// pipeline — phase A (WhAh+WlAh on Bh) overlaps Bl's flight; phase B (WhAl on
// Bl) overlaps Bh(next)'s flight; s_waitcnt vmcnt(6) never drains to 0
// (dummy-dest loads keep per-wave counts uniform at edges).
// Verified-dead ends: NW=8 blocks (occupancy collapse x2), 32x32x16 shape
// (same MFMA busy, +conflicts), launch_bounds(512,6) (VGPR cap 40 -> spill).

// ---------------- x: NCHW fp32 -> NHWC hi/lo bf16 (512 ch)
__global__ void k_x_split(const float* __restrict__ in, bf16* __restrict__ out) {
  __shared__ float t[32][33];
  const int b = blockIdx.z;
  const int p0 = blockIdx.x << 5, c0 = blockIdx.y << 5;
  const int tx = threadIdx.x, ty = threadIdx.y;  // block (32,8)
  const float* ib = in + (size_t)b * 256 * 16384;
  bf16* ob = out + (size_t)b * 16384 * 512;
#pragma unroll
  for (int k = 0; k < 32; k += 8)
    t[ty + k][tx] = ib[(size_t)(c0 + ty + k) * 16384 + p0 + tx];
  __syncthreads();
#pragma unroll
  for (int k = 0; k < 32; k += 8) {
    float v = t[tx][ty + k];
    bf16 hv = (bf16)v;
    bf16 lv = (bf16)(v - (float)hv);
    ob[(size_t)(p0 + ty + k) * 512 + c0 + tx] = hv;
    ob[(size_t)(p0 + ty + k) * 512 + 256 + c0 + tx] = lv;
  }
}

// ---------------- weight repack fp32 OIHW -> bf16 [2*tap+s][ci_chunk][co][32ci]
__global__ void k_repack2(const float* __restrict__ src, bf16* __restrict__ dst,
                          int Cout, int Cin, int taps, int coutTotal, int coff) {
  int tid = blockIdx.x * 256 + threadIdx.x;
  int total = Cout * Cin * taps;
  if (tid >= total) return;
  int t = tid % taps;
  int rest = tid / taps;
  int ci = rest % Cin;
  int co = rest / Cin;
  float w = src[tid];
  bf16 wh = (bf16)w;
  bf16 wl = (bf16)(w - (float)wh);
  int nchunk = Cin >> 5;
  size_t segsz = (size_t)coutTotal * Cin;  // = nchunk*coutTotal*32
  size_t base = (((size_t)(2 * t) * nchunk + (ci >> 5)) * coutTotal + coff + co) * 32
                + (ci & 31);
  dst[base] = wh;
  dst[base + segsz] = wl;
}

// ---------------- BN coefficients
__global__ void k_bncoef(const float* __restrict__ g, const float* __restrict__ b,
                         const float* __restrict__ m, const float* __restrict__ v,
                         float* __restrict__ sc, float* __restrict__ sh, int n) {
  int c = blockIdx.x * 256 + threadIdx.x;
  if (c >= n) return;
  float s = g[c] * (1.0f / sqrtf(v[c] + 1e-5f));
  sc[c] = s;
  sh[c] = b[c] - m[c] * s;
}

// ---------------- implicit-GEMM conv, half-slab counted-vmcnt pipeline
template <int NTAPS>
__global__ __launch_bounds__(256, 3)
void k_conv(const bf16* __restrict__ in, int Cin, int rowStride,
            const bf16* __restrict__ Wr, int Cout,
            const float* __restrict__ scale, const float* __restrict__ shift,
            const bf16* __restrict__ addbuf, int relu,
            int out_mode, void* __restrict__ out) {
  constexpr int R = (NTAPS == 9) ? 3 : 1;
  // plane = hl*R + r; 132 rows/plane: row p holds pos wi=p-1 (p=0,129 zero pad)
  __shared__ bf16 b_slab[2 * R * 132 * 32];
  __shared__ bf16 dummy_lds[512];  // sink for OOB-plane loads (count uniformity)
  const int bx = blockIdx.x;
  const int bb = bx & 7, h = (bx >> 3) & 127;   // XCD swizzle: batch == XCD
  const int row = bb * 128 + h;
  const int co_block = blockIdx.y << 7;
  const int tid = threadIdx.x;
  const int lane = tid & 63, wave = tid >> 6;
  const int wm = (wave >> 1) << 6, wn = (wave & 1) << 6;
  const int quad = lane >> 4, l15 = lane & 15;
  const int nchunk = Cin >> 5;
  const size_t segsz = (size_t)Cout * Cin;  // seg stride in repacked weights

  f32x4 acc[4][4];
#pragma unroll
  for (int i = 0; i < 4; ++i)
#pragma unroll
    for (int j = 0; j < 4; ++j)
#pragma unroll
      for (int r = 0; r < 4; ++r) acc[i][j][r] = 0.0f;

  // ---- one-time zeroing: pad rows (p=0,129) of all planes; OOB edge planes
  {
    uint4 z; z.x = z.y = z.z = z.w = 0u;
    for (int u = tid; u < 2 * R * 2 * 4; u += 256) {
      int g = u & 3, e = (u >> 2) & 1, plane = u >> 3;
      bf16* d = &b_slab[((size_t)plane * 132 + (e ? 129 : 0)) * 32 + g * 8];
      *(uint4*)d = z;
    }
    if (R == 3 && (h == 0 || h == 127)) {
      int rr = (h == 0) ? 0 : 2;
      for (int u = tid; u < 2 * 132 * 4; u += 256) {
        int g = u & 3, p = (u >> 2) % 132, hl = (u >> 2) / 132;
        bf16* d = &b_slab[((size_t)(hl * R + rr) * 132 + p) * 32 + g * 8];
        *(uint4*)d = z;
      }
    }
  }
  __syncthreads();  // pads visible before any slab read

  // ---- half-slab async stage: hl half of chunk cb. OOB planes -> dummy dest
  // (keeps per-wave outstanding-load count uniform so vmcnt immediates hold).
  auto stage_half = [&](int hl, int cb) {
    for (int u = wave; u < R * 8; u += 4) {
      int rr = u >> 3, sub = u & 7;
      int plane = hl * R + rr;
      int hi = h + rr - (R == 3 ? 1 : 0);
      bool ok = (unsigned)hi < 128u;           // block-uniform
      int hic = ok ? hi : h;
      int p = 1 + sub * 16 + (lane >> 2);      // row this lane covers
      int gsw = (lane & 3) ^ ((p >> 1) & 3);   // source granule (swizzle on src)
      const bf16* src = in + (size_t)((bb * 128 + hic) * 128 + (p - 1)) * rowStride
                        + (size_t)hl * Cin + cb + gsw * 8;
      bf16* dst = ok ? &b_slab[(size_t)(plane * 132 + 1 + sub * 16) * 32]
                     : dummy_lds;
      __builtin_amdgcn_global_load_lds(
          (const __attribute__((address_space(1))) uint32_t*)src,
          (__attribute__((address_space(3))) uint32_t*)dst, 16, 0, 0);
    }
  };

#define WAIT_VM()                                                        \
  do {                                                                   \
    __builtin_amdgcn_sched_barrier(0);                                   \
    if constexpr (R == 3) asm volatile("s_waitcnt vmcnt(6)" ::: "memory"); \
    else                  asm volatile("s_waitcnt vmcnt(2)" ::: "memory"); \
    __builtin_amdgcn_sched_barrier(0);                                   \
  } while (0)

  stage_half(0, 0);  // Bh(0)
  stage_half(1, 0);  // Bl(0)

  for (int cb = 0; cb < Cin; cb += 32) {
    // ======== phase A: WhAh + WlAh on Bh(cb); Bl(cb) still in flight ========
    WAIT_VM();                         // my Bh(cb) loads landed
    __builtin_amdgcn_s_barrier();      // everyone's landed
#pragma unroll
    for (int tap = 0; tap < NTAPS; ++tap) {
      const int rr = (R == 3) ? (tap / 3) : 0;
      const int wc = (R == 3) ? (tap % 3) : 1;
      const int bH = rr * 132;
      const int p0 = wn + l15 + wc;
      const int sw8 = (((p0 >> 1) & 3) ^ quad) << 3;
      const bf16* Ah = Wr + (((size_t)(2 * tap) * nchunk + (cb >> 5)) * Cout
                             + co_block + wm + l15) * 32 + quad * 8;
      const bf16* Al = Ah + segsz;
      bf16x8 afH[4], afL[4], bfH[4];
#pragma unroll
      for (int i = 0; i < 4; ++i) {
        afH[i] = *(const bf16x8*)(Ah + (size_t)i * 16 * 32);
        afL[i] = *(const bf16x8*)(Al + (size_t)i * 16 * 32);
      }
#pragma unroll
      for (int j = 0; j < 4; ++j)
        bfH[j] = *(const bf16x8*)&b_slab[(size_t)(bH + p0 + j * 16) * 32 + sw8];
      __builtin_amdgcn_s_setprio(1);
#pragma unroll
      for (int i = 0; i < 4; ++i)
#pragma unroll
        for (int j = 0; j < 4; ++j) {
          acc[i][j] = __builtin_amdgcn_mfma_f32_16x16x32_bf16(afH[i], bfH[j], acc[i][j], 0, 0, 0);
          acc[i][j] = __builtin_amdgcn_mfma_f32_16x16x32_bf16(afL[i], bfH[j], acc[i][j], 0, 0, 0);
        }
      __builtin_amdgcn_s_setprio(0);
    }
    __builtin_amdgcn_s_barrier();      // all done reading Bh(cb)
    {                                  // refill Bh with next chunk (clamped:
      int nb = (cb + 32 < Cin) ? cb + 32 : cb;  // last iter re-loads same data)
      stage_half(0, nb);
    }
    // ======== phase B: WhAl on Bl(cb); Bh(next) in flight ========
    WAIT_VM();                         // my Bl(cb) loads landed
    __builtin_amdgcn_s_barrier();
#pragma unroll
    for (int tap = 0; tap < NTAPS; ++tap) {
      const int rr = (R == 3) ? (tap / 3) : 0;
      const int wc = (R == 3) ? (tap % 3) : 1;
      const int bL = (R + rr) * 132;
      const int p0 = wn + l15 + wc;
      const int sw8 = (((p0 >> 1) & 3) ^ quad) << 3;
      const bf16* Ah = Wr + (((size_t)(2 * tap) * nchunk + (cb >> 5)) * Cout
                             + co_block + wm + l15) * 32 + quad * 8;
      bf16x8 afH[4], bfL[4];
#pragma unroll
      for (int i = 0; i < 4; ++i)
        afH[i] = *(const bf16x8*)(Ah + (size_t)i * 16 * 32);
#pragma unroll
      for (int j = 0; j < 4; ++j)
        bfL[j] = *(const bf16x8*)&b_slab[(size_t)(bL + p0 + j * 16) * 32 + sw8];
      __builtin_amdgcn_s_setprio(1);
#pragma unroll
      for (int i = 0; i < 4; ++i)
#pragma unroll
        for (int j = 0; j < 4; ++j)
          acc[i][j] = __builtin_amdgcn_mfma_f32_16x16x32_bf16(afH[i], bfL[j], acc[i][j], 0, 0, 0);
      __builtin_amdgcn_s_setprio(0);
    }
    __builtin_amdgcn_s_barrier();      // all done reading Bl(cb)
    if (cb + 32 < Cin) stage_half(1, cb + 32);
  }
#undef WAIT_VM

  // epilogue: D row(m=cout)=quad*4+reg, col(n=pos)=lane&15
#pragma unroll
  for (int i = 0; i < 4; ++i) {
    const int co = co_block + wm + i * 16 + (quad << 2);
#pragma unroll
    for (int j = 0; j < 4; ++j) {
      const int pos = wn + j * 16 + l15;
      float v[4];
#pragma unroll
      for (int r = 0; r < 4; ++r) v[r] = acc[i][j][r];
      if (scale) {
#pragma unroll
        for (int r = 0; r < 4; ++r) v[r] = v[r] * scale[co + r] + shift[co + r];
      }
      if (addbuf) {
        const bf16* ah = addbuf + (size_t)(row * 128 + pos) * (2 * Cout) + co;
        const bf16* al = ah + Cout;
#pragma unroll
        for (int r = 0; r < 4; ++r) v[r] += (float)ah[r] + (float)al[r];
      }
      if (relu) {
#pragma unroll
        for (int r = 0; r < 4; ++r) v[r] = fmaxf(v[r], 0.0f);
      }
      if (out_mode == 0) {
        bf16* ob = (bf16*)out;
        union { bf16 hv[4]; uint2 u; } ph, pl;
#pragma unroll
        for (int r = 0; r < 4; ++r) {
          ph.hv[r] = (bf16)v[r];
          pl.hv[r] = (bf16)(v[r] - (float)ph.hv[r]);
        }
        const size_t base = (size_t)(row * 128 + pos) * (2 * Cout);
        *(uint2*)&ob[base + co] = ph.u;
        *(uint2*)&ob[base + Cout + co] = pl.u;
      } else if (out_mode == 1) {
        float* of = (float*)out;
        float4 pk = make_float4(v[0], v[1], v[2], v[3]);
        *(float4*)&of[(size_t)(row * 128 + pos) * Cout + co] = pk;
      } else {
        float* of = (float*)out;
#pragma unroll
        for (int r = 0; r < 4; ++r)
          of[((size_t)(bb * Cout + co + r) * 128 + h) * 128 + pos] = v[r];
      }
    }
  }
}

// ---------------- pools (fp32 reconstruct, scan, re-split), in-place
// y: 512ch rows [lookH 0:128 | pH 128:256 | lookL 256:384 | pL 384:512]
__global__ void k_pool_s1(bf16* __restrict__ y) {  // left_pool: scan w
  int tid = blockIdx.x * 256 + threadIdx.x;
  int c = tid & 127, h = (tid >> 7) & 127, b = tid >> 14;
  bf16* base = y + (size_t)((b * 128 + h) * 128) * 512;
  float run = -INFINITY;
  for (int w = 127; w >= 0; --w) {
    bf16* p = base + (size_t)w * 512;
    float look = (float)p[c] + (float)p[256 + c];
    float padd = (float)p[128 + c] + (float)p[384 + c];
    run = fmaxf(run, look);
    float sum = run + padd;
    bf16 hv = (bf16)sum;
    p[c] = hv;
    p[128 + c] = (bf16)(sum - (float)hv);
  }
}
__global__ void k_pool_s2(bf16* __restrict__ y) {  // top_pool: scan h
  int tid = blockIdx.x * 256 + threadIdx.x;
  int c = tid & 127, w = (tid >> 7) & 127, b = tid >> 14;
  bf16* base = y + ((size_t)b * 16384 + w) * 512;
  float run = -INFINITY;
  for (int hh = 127; hh >= 0; --hh) {
    bf16* p = base + (size_t)hh * 65536;
    float look = (float)p[c] + (float)p[256 + c];
    float padd = (float)p[128 + c] + (float)p[384 + c];
    run = fmaxf(run, look);
    float sum = run + padd;
    bf16 hv = (bf16)sum;
    p[c] = hv;
    p[128 + c] = (bf16)(sum - (float)hv);
  }
}
__global__ void k_tpool_f(float* __restrict__ buf) {  // in-place top_pool fp32
  int tid = blockIdx.x * 256 + threadIdx.x;
  int c = tid & 127, w = (tid >> 7) & 127, b = tid >> 14;
  float* p = buf + ((size_t)b * 16384 + w) * 128 + c;
  float run = -INFINITY;
  for (int hh = 127; hh >= 0; --hh) {
    run = fmaxf(run, p[(size_t)hh * 16384]);
    p[(size_t)hh * 16384] = run;
  }
}
__global__ void k_lpool_add_f(const float* __restrict__ in, const float* __restrict__ addb,
                              bf16* __restrict__ out) {
  int tid = blockIdx.x * 256 + threadIdx.x;
  int c = tid & 127, h = (tid >> 7) & 127, b = tid >> 14;
  const float* p = in + (size_t)((b * 128 + h) * 128) * 128 + c;
  const float* a = addb + (size_t)((b * 128 + h) * 128) * 128 + c;
  bf16* o = out + (size_t)((b * 128 + h) * 128) * 256;
  float run = -INFINITY;
  for (int w = 127; w >= 0; --w) {
    run = fmaxf(run, p[(size_t)w * 128]);
    float sum = run + a[(size_t)w * 128];
    bf16 hv = (bf16)sum;
    o[(size_t)w * 256 + c] = hv;
    o[(size_t)w * 256 + 128 + c] = (bf16)(sum - (float)hv);
  }
}

extern "C" void kernel_launch(void* const* d_in, const int* in_sizes, int n_in,
                              void* d_out, int out_size, void* d_ws, size_t ws_size,
                              hipStream_t stream) {
  (void)in_sizes; (void)n_in; (void)out_size; (void)ws_size;
#define INF(i) ((const float*)d_in[i])
  char* ws = (char*)d_ws;
  const size_t MB = 1 << 20;
  // weights [0, ~9.75MB): [2*tap+s][ci_chunk][co][32]
  bf16* wrA  = (bf16*)(ws + 0);          // 18*256*256
  bf16* wrB  = (bf16*)(ws + 2359296);
  bf16* wrp1 = (bf16*)(ws + 4718592);    // 18*128*128
  bf16* wrp2 = (bf16*)(ws + 5308416);
  bf16* wrpc = (bf16*)(ws + 5898240);    // 18*256*128
  bf16* wrc1 = (bf16*)(ws + 7077888);    // 2*256*256
  bf16* wrc2 = (bf16*)(ws + 7340032);    // 18*256*256
  float* scA  = (float*)(ws + 9699328);
  float* shA  = (float*)(ws + 9703424);
  float* scB  = (float*)(ws + 9707520);
  float* shB  = (float*)(ws + 9711616);
  float* scp  = (float*)(ws + 9715712);
  float* shp  = (float*)(ws + 9719808);
  float* scb  = (float*)(ws + 9723904);
  float* shb  = (float*)(ws + 9728000);
  float* scc2 = (float*)(ws + 9732096);
  float* shc2 = (float*)(ws + 9736192);
  // activations (ws use <= 330 MB; d_out doubles as 128 MB scratch)
  bf16*  x_hl  = (bf16*)(ws + 10 * MB);    // 128 MB, live thru step 8
  bf16*  bnrel = (bf16*)(ws + 138 * MB);   // 128 MB: bn1 -> relu1 in-place
  float* p1lk  = (float*)(ws + 266 * MB);  // 64 MB fp32
  float* p2lk  = (float*)(ws + 10 * MB);   // 64 MB fp32 over dead x_hl
  bf16*  psum  = (bf16*)(ws + 74 * MB);    // 64 MB hi/lo compact 256ch
  bf16*  yscr  = (bf16*)d_out;             // 128 MB scratch: yA/s1 then yB/s2

  // 1) x -> NHWC hi/lo
  k_x_split<<<dim3(512, 8, 8), dim3(32, 8), 0, stream>>>(INF(0), x_hl);

  // 2) weight repacks (Wh/Wl segments)
  k_repack2<<<1152, 256, 0, stream>>>(INF(1),  wrA,  128, 256, 9, 256, 0);
  k_repack2<<<1152, 256, 0, stream>>>(INF(6),  wrA,  128, 256, 9, 256, 128);
  k_repack2<<<1152, 256, 0, stream>>>(INF(11), wrB,  128, 256, 9, 256, 0);
  k_repack2<<<1152, 256, 0, stream>>>(INF(16), wrB,  128, 256, 9, 256, 128);
  k_repack2<<<576,  256, 0, stream>>>(INF(21), wrp1, 128, 128, 9, 128, 0);
  k_repack2<<<576,  256, 0, stream>>>(INF(22), wrp2, 128, 128, 9, 128, 0);
  k_repack2<<<1152, 256, 0, stream>>>(INF(23), wrpc, 256, 128, 9, 256, 0);
  k_repack2<<<256,  256, 0, stream>>>(INF(28), wrc1, 256, 256, 1, 256, 0);
  k_repack2<<<2304, 256, 0, stream>>>(INF(33), wrc2, 256, 256, 9, 256, 0);

  // 3) BN coefficients
  k_bncoef<<<1, 256, 0, stream>>>(INF(2),  INF(3),  INF(4),  INF(5),  scA,       shA,       128);
  k_bncoef<<<1, 256, 0, stream>>>(INF(7),  INF(8),  INF(9),  INF(10), scA + 128, shA + 128, 128);
  k_bncoef<<<1, 256, 0, stream>>>(INF(12), INF(13), INF(14), INF(15), scB,       shB,       128);
  k_bncoef<<<1, 256, 0, stream>>>(INF(17), INF(18), INF(19), INF(20), scB + 128, shB + 128, 128);
  k_bncoef<<<1, 256, 0, stream>>>(INF(24), INF(25), INF(26), INF(27), scp, shp, 256);
  k_bncoef<<<1, 256, 0, stream>>>(INF(29), INF(30), INF(31), INF(32), scb, shb, 256);
  k_bncoef<<<1, 256, 0, stream>>>(INF(34), INF(35), INF(36), INF(37), scc2, shc2, 256);

  // 4) bn1 = BN(conv1x1(x)) -> bnrel (hi/lo)
  k_conv<1><<<dim3(1024, 2), 256, 0, stream>>>(x_hl, 256, 512, wrc1, 256, scb, shb, nullptr, 0, 0, bnrel);
  // 5) yA = [look_conv1 | p1_conv1] (BN+ReLU) -> d_out scratch
  k_conv<9><<<dim3(1024, 2), 256, 0, stream>>>(x_hl, 256, 512, wrA, 256, scA, shA, nullptr, 1, 0, yscr);
  // 6) s1 = left_pool(look1) + p1_conv1 (in-place, ch [0:256))
  k_pool_s1<<<512, 256, 0, stream>>>(yscr);
  // 7) p1_look = conv(s1, p1lc) -> fp32
  k_conv<9><<<dim3(1024, 1), 256, 0, stream>>>(yscr, 128, 512, wrp1, 128, nullptr, nullptr, nullptr, 0, 1, p1lk);
  // 8) yB = [look_conv2 | p2_conv1] -> d_out scratch (x dead after)
  k_conv<9><<<dim3(1024, 2), 256, 0, stream>>>(x_hl, 256, 512, wrB, 256, scB, shB, nullptr, 1, 0, yscr);
  // 9) s2 = top_pool(look2) + p2_conv1 (in-place)
  k_pool_s2<<<512, 256, 0, stream>>>(yscr);
  // 10) p2_look = conv(s2, p2lc) -> fp32 (over dead x_hl)
  k_conv<9><<<dim3(1024, 1), 256, 0, stream>>>(yscr, 128, 512, wrp2, 128, nullptr, nullptr, nullptr, 0, 1, p2lk);
  // 11) ptmp = top_pool(p1_look) in-place
  k_tpool_f<<<512, 256, 0, stream>>>(p1lk);
  // 12) psum = left_pool(p2_look) + ptmp -> hi/lo compact
  k_lpool_add_f<<<512, 256, 0, stream>>>(p2lk, p1lk, psum);
  // 13) relu1 = relu(BN(conv(psum, pconv1)) + bn1) in-place over bn1
  k_conv<9><<<dim3(1024, 2), 256, 0, stream>>>(psum, 128, 256, wrpc, 256, scp, shp, bnrel, 1, 0, bnrel);
  // 14) out = relu(BN(conv(relu1, c2))) -> NCHW fp32 d_out
  k_conv<9><<<dim3(1024, 2), 256, 0, stream>>>(bnrel, 256, 512, wrc2, 256, scc2, shc2, nullptr, 1, 2, (float*)d_out);
#undef INF
}

// Round 8
// 2206.020 us; speedup vs baseline: 1.1778x; 1.1778x over previous
//
#include <hip/hip_runtime.h>
#include <hip/hip_bf16.h>
#include <stdint.h>
#include <math.h>

typedef __bf16 bf16;
typedef __bf16 bf16x8 __attribute__((ext_vector_type(8)));
typedef float f32x4 __attribute__((ext_vector_type(4)));

// B=8, H=W=128, dim=256, mid=128. fp32 I/O; internal hi/lo bf16 pairs.
// conv = 3-term bf16 (WhAh + WhAl + WlAh) on 16x16x32 MFMA. A (weights)
// loaded global->reg per tap from fragment-major repack [2*tap+s][chunk][co][32ci].
// B: 64-pos double-buffered LDS slab staged via global_load_lds w=16 (linear
// dest + swizzled global src). Stage for chunk c+1 issues inside chunk c's LAST
// tap, AFTER that tap's A/B frag loads (vmcnt retires in order -> A-waits count
// past the stage) and BEFORE its MFMA (sched_barrier-pinned) -> the barrier
// drain is covered by the last tap's MFMA; taps 0..N-2 see no stage loads.
// Ledger: NW=8 blocks ✗✗ (occupancy), 32x32x16 ✗ (same MFMA busy, +conflicts),
// launch_bounds(512,6) ✗ (VGPR cap 40, spill), half-slab phase split ✗ (4
// barriers + A x2, MfmaUtil 38). Round-6 base: 432 us convs, conflicts 0.

// ---------------- x: NCHW fp32 -> NHWC hi/lo bf16 (512 ch)
__global__ void k_x_split(const float* __restrict__ in, bf16* __restrict__ out) {
  __shared__ float t[32][33];
  const int b = blockIdx.z;
  const int p0 = blockIdx.x << 5, c0 = blockIdx.y << 5;
  const int tx = threadIdx.x, ty = threadIdx.y;  // block (32,8)
  const float* ib = in + (size_t)b * 256 * 16384;
  bf16* ob = out + (size_t)b * 16384 * 512;
#pragma unroll
  for (int k = 0; k < 32; k += 8)
    t[ty + k][tx] = ib[(size_t)(c0 + ty + k) * 16384 + p0 + tx];
  __syncthreads();
#pragma unroll
  for (int k = 0; k < 32; k += 8) {
    float v = t[tx][ty + k];
    bf16 hv = (bf16)v;
    bf16 lv = (bf16)(v - (float)hv);
    ob[(size_t)(p0 + ty + k) * 512 + c0 + tx] = hv;
    ob[(size_t)(p0 + ty + k) * 512 + 256 + c0 + tx] = lv;
  }
}

// ---------------- weight repack fp32 OIHW -> bf16 [2*tap+s][ci_chunk][co][32ci]
__global__ void k_repack2(const float* __restrict__ src, bf16* __restrict__ dst,
                          int Cout, int Cin, int taps, int coutTotal, int coff) {
  int tid = blockIdx.x * 256 + threadIdx.x;
  int total = Cout * Cin * taps;
  if (tid >= total) return;
  int t = tid % taps;
  int rest = tid / taps;
  int ci = rest % Cin;
  int co = rest / Cin;
  float w = src[tid];
  bf16 wh = (bf16)w;
  bf16 wl = (bf16)(w - (float)wh);
  int nchunk = Cin >> 5;
  size_t segsz = (size_t)coutTotal * Cin;  // = nchunk*coutTotal*32
  size_t base = (((size_t)(2 * t) * nchunk + (ci >> 5)) * coutTotal + coff + co) * 32
                + (ci & 31);
  dst[base] = wh;
  dst[base + segsz] = wl;
}

// ---------------- BN coefficients
__global__ void k_bncoef(const float* __restrict__ g, const float* __restrict__ b,
                         const float* __restrict__ m, const float* __restrict__ v,
                         float* __restrict__ sc, float* __restrict__ sh, int n) {
  int c = blockIdx.x * 256 + threadIdx.x;
  if (c >= n) return;
  float s = g[c] * (1.0f / sqrtf(v[c] + 1e-5f));
  sc[c] = s;
  sh[c] = b[c] - m[c] * s;
}

// ---------------- implicit-GEMM conv, 64-pos dbuf slab, last-tap stage overlap
// Block = 128 cout x 64 pos; 4 waves stacked on cout (32 co x 64 pos each).
template <int NTAPS>
__global__ __launch_bounds__(256, 3)
void k_conv(const bf16* __restrict__ in, int Cin, int rowStride,
            const bf16* __restrict__ Wr, int Cout,
            const float* __restrict__ scale, const float* __restrict__ shift,
            const bf16* __restrict__ addbuf, int relu,
            int out_mode, void* __restrict__ out) {
  constexpr int R = (NTAPS == 9) ? 3 : 1;
  constexpr int PL = 2 * R;              // planes per buffer (hl x R)
  constexpr int BUF = PL * 66 * 32;      // elems per buffer; rows p: pos w0+p-1
  __shared__ bf16 b_slab[2 * BUF];
  const int bx = blockIdx.x;
  const int bb = bx & 7, h = (bx >> 3) & 127;   // XCD swizzle: batch == XCD
  const int w0 = (bx >> 10) << 6;               // 64-pos segment
  const int row = bb * 128 + h;
  const int co_block = blockIdx.y << 7;
  const int tid = threadIdx.x;
  const int lane = tid & 63, wave = tid >> 6;
  const int quad = lane >> 4, l15 = lane & 15;
  const int nchunk = Cin >> 5;
  const size_t segsz = (size_t)Cout * Cin;  // seg stride in repacked weights

  f32x4 acc[2][4];
#pragma unroll
  for (int i = 0; i < 2; ++i)
#pragma unroll
    for (int j = 0; j < 4; ++j)
#pragma unroll
      for (int r = 0; r < 4; ++r) acc[i][j][r] = 0.0f;

  // ---- one-time zeroing of never-loaded slots, BOTH buffers:
  // rows 0 & 65 of every plane (one of them is loaded later; harmless), and
  // full h-OOB edge planes.
  {
    uint4 z; z.x = z.y = z.z = z.w = 0u;
    for (int u = tid; u < 2 * PL * 2 * 4; u += 256) {
      int g = u & 3, e = (u >> 2) & 1, plane = (u >> 3) % PL, bs = u / (PL * 8);
      bf16* d = &b_slab[(size_t)bs * BUF + ((size_t)plane * 66 + (e ? 65 : 0)) * 32 + g * 8];
      *(uint4*)d = z;
    }
    if (R == 3 && (h == 0 || h == 127)) {
      int rr = (h == 0) ? 0 : 2;
      for (int u = tid; u < 2 * 2 * 66 * 4; u += 256) {
        int g = u & 3, p = (u >> 2) % 66, hl = ((u >> 2) / 66) & 1, bs = u / (2 * 66 * 4);
        bf16* d = &b_slab[(size_t)bs * BUF + ((size_t)(hl * R + rr) * 66 + p) * 32 + g * 8];
        *(uint4*)d = z;
      }
    }
  }

  const int s0 = (w0 == 0) ? 1 : 0;   // main-stage start row (skip OOB pos -1)
  const int pt = (w0 == 0) ? 65 : 64; // tail row (the one not covered by main)
  const int wt = w0 + pt - 1;         // its pos: 64 or 127 (always in-bounds)

  // ---- stage one chunk into buf: 4 full-wave loads + 1 quad-lane tail / plane
  auto stage = [&](bf16* buf, int cb) {
    for (int u = wave; u < PL * 4; u += 4) {
      int plane = u >> 2, sub = u & 3;
      int hl = plane >= R ? 1 : 0, rr = plane - hl * R;
      int hi = h + rr - (R == 3 ? 1 : 0);
      if ((unsigned)hi < 128u) {
        int p = s0 + sub * 16 + (lane >> 2);
        int gsw = (lane & 3) ^ ((p >> 1) & 3);   // swizzle folded into src
        const bf16* src = in + (size_t)((bb * 128 + hi) * 128 + (w0 + p - 1)) * rowStride
                          + (size_t)hl * Cin + cb + gsw * 8;
        bf16* dst = buf + ((size_t)plane * 66 + s0 + sub * 16) * 32;
        __builtin_amdgcn_global_load_lds(
            (const __attribute__((address_space(1))) uint32_t*)src,
            (__attribute__((address_space(3))) uint32_t*)dst, 16, 0, 0);
      }
    }
    if (lane < 4) {
      for (int plane = wave; plane < PL; plane += 4) {
        int hl = plane >= R ? 1 : 0, rr = plane - hl * R;
        int hi = h + rr - (R == 3 ? 1 : 0);
        if ((unsigned)hi < 128u) {
          int gsw = lane ^ ((pt >> 1) & 3);
          const bf16* src = in + (size_t)((bb * 128 + hi) * 128 + wt) * rowStride
                            + (size_t)hl * Cin + cb + gsw * 8;
          bf16* dst = buf + ((size_t)plane * 66 + pt) * 32;
          __builtin_amdgcn_global_load_lds(
              (const __attribute__((address_space(1))) uint32_t*)src,
              (__attribute__((address_space(3))) uint32_t*)dst, 16, 0, 0);
        }
      }
    }
  };

  stage(b_slab, 0);
  __syncthreads();  // buf0 ready; zero-init visible

  int cur = 0;
  for (int cb = 0; cb < Cin; cb += 32) {
    bf16* bufc = b_slab + (size_t)cur * BUF;
#pragma unroll
    for (int tap = 0; tap < NTAPS; ++tap) {
      const int rr = (R == 3) ? (tap / 3) : 0;
      const int wc = (R == 3) ? (tap % 3) : 1;
      const int p0 = l15 + wc;
      const int sw8 = (((p0 >> 1) & 3) ^ quad) << 3;  // j*16 preserves (p>>1)&3
      // A fragments from L2; fragment-major: lane addr = l15*64B + quad*16B
      const bf16* Af = Wr + (((size_t)(2 * tap) * nchunk + (cb >> 5)) * Cout
                             + co_block + wave * 32 + l15) * 32 + quad * 8;
      bf16x8 afH[2], afL[2], bfH[4], bfL[4];
#pragma unroll
      for (int i = 0; i < 2; ++i) {
        afH[i] = *(const bf16x8*)(Af + (size_t)i * 16 * 32);
        afL[i] = *(const bf16x8*)(Af + segsz + (size_t)i * 16 * 32);
      }
#pragma unroll
      for (int j = 0; j < 4; ++j) {
        const int p_idx = p0 + j * 16;
        bfH[j] = *(const bf16x8*)&bufc[((size_t)rr * 66 + p_idx) * 32 + sw8];
        bfL[j] = *(const bf16x8*)&bufc[((size_t)(R + rr) * 66 + p_idx) * 32 + sw8];
      }
      if (tap == NTAPS - 1 && cb + 32 < Cin) {
        // issue next-chunk stage AFTER this tap's frag loads (in-order vmcnt:
        // A-waits count past these), BEFORE its MFMA (drain covered by MFMA)
        __builtin_amdgcn_sched_barrier(0);
        stage(b_slab + (size_t)(cur ^ 1) * BUF, cb + 32);
        __builtin_amdgcn_sched_barrier(0);
      }
#pragma unroll
      for (int i = 0; i < 2; ++i)
#pragma unroll
        for (int j = 0; j < 4; ++j) {
          acc[i][j] = __builtin_amdgcn_mfma_f32_16x16x32_bf16(afH[i], bfH[j], acc[i][j], 0, 0, 0);
          acc[i][j] = __builtin_amdgcn_mfma_f32_16x16x32_bf16(afH[i], bfL[j], acc[i][j], 0, 0, 0);
          acc[i][j] = __builtin_amdgcn_mfma_f32_16x16x32_bf16(afL[i], bfH[j], acc[i][j], 0, 0, 0);
        }
    }
    __syncthreads();  // next buf ready; all reads of bufc done
    cur ^= 1;
  }

  // epilogue: D row(m=cout)=quad*4+reg, col(n=pos)=lane&15
#pragma unroll
  for (int i = 0; i < 2; ++i) {
    const int co = co_block + wave * 32 + i * 16 + (quad << 2);
#pragma unroll
    for (int j = 0; j < 4; ++j) {
      const int pos = w0 + j * 16 + l15;
      float v[4];
#pragma unroll
      for (int r = 0; r < 4; ++r) v[r] = acc[i][j][r];
      if (scale) {
#pragma unroll
        for (int r = 0; r < 4; ++r) v[r] = v[r] * scale[co + r] + shift[co + r];
      }
      if (addbuf) {
        const bf16* ah = addbuf + (size_t)(row * 128 + pos) * (2 * Cout) + co;
        const bf16* al = ah + Cout;
#pragma unroll
        for (int r = 0; r < 4; ++r) v[r] += (float)ah[r] + (float)al[r];
      }
      if (relu) {
#pragma unroll
        for (int r = 0; r < 4; ++r) v[r] = fmaxf(v[r], 0.0f);
      }
      if (out_mode == 0) {
        bf16* ob = (bf16*)out;
        union { bf16 hv[4]; uint2 u; } ph, pl;
#pragma unroll
        for (int r = 0; r < 4; ++r) {
          ph.hv[r] = (bf16)v[r];
          pl.hv[r] = (bf16)(v[r] - (float)ph.hv[r]);
        }
        const size_t base = (size_t)(row * 128 + pos) * (2 * Cout);
        *(uint2*)&ob[base + co] = ph.u;
        *(uint2*)&ob[base + Cout + co] = pl.u;
      } else if (out_mode == 1) {
        float* of = (float*)out;
        float4 pk = make_float4(v[0], v[1], v[2], v[3]);
        *(float4*)&of[(size_t)(row * 128 + pos) * Cout + co] = pk;
      } else {
        float* of = (float*)out;
#pragma unroll
        for (int r = 0; r < 4; ++r)
          of[((size_t)(bb * Cout + co + r) * 128 + h) * 128 + pos] = v[r];
      }
    }
  }
}

// ---------------- pools (fp32 reconstruct, scan, re-split), in-place
// y: 512ch rows [lookH 0:128 | pH 128:256 | lookL 256:384 | pL 384:512]
__global__ void k_pool_s1(bf16* __restrict__ y) {  // left_pool: scan w
  int tid = blockIdx.x * 256 + threadIdx.x;
  int c = tid & 127, h = (tid >> 7) & 127, b = tid >> 14;
  bf16* base = y + (size_t)((b * 128 + h) * 128) * 512;
  float run = -INFINITY;
  for (int w = 127; w >= 0; --w) {
    bf16* p = base + (size_t)w * 512;
    float look = (float)p[c] + (float)p[256 + c];
    float padd = (float)p[128 + c] + (float)p[384 + c];
    run = fmaxf(run, look);
    float sum = run + padd;
    bf16 hv = (bf16)sum;
    p[c] = hv;
    p[128 + c] = (bf16)(sum - (float)hv);
  }
}
__global__ void k_pool_s2(bf16* __restrict__ y) {  // top_pool: scan h
  int tid = blockIdx.x * 256 + threadIdx.x;
  int c = tid & 127, w = (tid >> 7) & 127, b = tid >> 14;
  bf16* base = y + ((size_t)b * 16384 + w) * 512;
  float run = -INFINITY;
  for (int hh = 127; hh >= 0; --hh) {
    bf16* p = base + (size_t)hh * 65536;
    float look = (float)p[c] + (float)p[256 + c];
    float padd = (float)p[128 + c] + (float)p[384 + c];
    run = fmaxf(run, look);
    float sum = run + padd;
    bf16 hv = (bf16)sum;
    p[c] = hv;
    p[128 + c] = (bf16)(sum - (float)hv);
  }
}
__global__ void k_tpool_f(float* __restrict__ buf) {  // in-place top_pool fp32
  int tid = blockIdx.x * 256 + threadIdx.x;
  int c = tid & 127, w = (tid >> 7) & 127, b = tid >> 14;
  float* p = buf + ((size_t)b * 16384 + w) * 128 + c;
  float run = -INFINITY;
  for (int hh = 127; hh >= 0; --hh) {
    run = fmaxf(run, p[(size_t)hh * 16384]);
    p[(size_t)hh * 16384] = run;
  }
}
__global__ void k_lpool_add_f(const float* __restrict__ in, const float* __restrict__ addb,
                              bf16* __restrict__ out) {
  int tid = blockIdx.x * 256 + threadIdx.x;
  int c = tid & 127, h = (tid >> 7) & 127, b = tid >> 14;
  const float* p = in + (size_t)((b * 128 + h) * 128) * 128 + c;
  const float* a = addb + (size_t)((b * 128 + h) * 128) * 128 + c;
  bf16* o = out + (size_t)((b * 128 + h) * 128) * 256;
  float run = -INFINITY;
  for (int w = 127; w >= 0; --w) {
    run = fmaxf(run, p[(size_t)w * 128]);
    float sum = run + a[(size_t)w * 128];
    bf16 hv = (bf16)sum;
    o[(size_t)w * 256 + c] = hv;
    o[(size_t)w * 256 + 128 + c] = (bf16)(sum - (float)hv);
  }
}

extern "C" void kernel_launch(void* const* d_in, const int* in_sizes, int n_in,
                              void* d_out, int out_size, void* d_ws, size_t ws_size,
                              hipStream_t stream) {
  (void)in_sizes; (void)n_in; (void)out_size; (void)ws_size;
#define INF(i) ((const float*)d_in[i])
  char* ws = (char*)d_ws;
  const size_t MB = 1 << 20;
  // weights [0, ~9.75MB): [2*tap+s][ci_chunk][co][32]
  bf16* wrA  = (bf16*)(ws + 0);          // 18*256*256
  bf16* wrB  = (bf16*)(ws + 2359296);
  bf16* wrp1 = (bf16*)(ws + 4718592);    // 18*128*128
  bf16* wrp2 = (bf16*)(ws + 5308416);
  bf16* wrpc = (bf16*)(ws + 5898240);    // 18*256*128
  bf16* wrc1 = (bf16*)(ws + 7077888);    // 2*256*256
  bf16* wrc2 = (bf16*)(ws + 7340032);    // 18*256*256
  float* scA  = (float*)(ws + 9699328);
  float* shA  = (float*)(ws + 9703424);
  float* scB  = (float*)(ws + 9707520);
  float* shB  = (float*)(ws + 9711616);
  float* scp  = (float*)(ws + 9715712);
  float* shp  = (float*)(ws + 9719808);
  float* scb  = (float*)(ws + 9723904);
  float* shb  = (float*)(ws + 9728000);
  float* scc2 = (float*)(ws + 9732096);
  float* shc2 = (float*)(ws + 9736192);
  // activations (ws use <= 330 MB; d_out doubles as 128 MB scratch)
  bf16*  x_hl  = (bf16*)(ws + 10 * MB);    // 128 MB, live thru step 8
  bf16*  bnrel = (bf16*)(ws + 138 * MB);   // 128 MB: bn1 -> relu1 in-place
  float* p1lk  = (float*)(ws + 266 * MB);  // 64 MB fp32
  float* p2lk  = (float*)(ws + 10 * MB);   // 64 MB fp32 over dead x_hl
  bf16*  psum  = (bf16*)(ws + 74 * MB);    // 64 MB hi/lo compact 256ch
  bf16*  yscr  = (bf16*)d_out;             // 128 MB scratch: yA/s1 then yB/s2

  // 1) x -> NHWC hi/lo
  k_x_split<<<dim3(512, 8, 8), dim3(32, 8), 0, stream>>>(INF(0), x_hl);

  // 2) weight repacks (Wh/Wl segments)
  k_repack2<<<1152, 256, 0, stream>>>(INF(1),  wrA,  128, 256, 9, 256, 0);
  k_repack2<<<1152, 256, 0, stream>>>(INF(6),  wrA,  128, 256, 9, 256, 128);
  k_repack2<<<1152, 256, 0, stream>>>(INF(11), wrB,  128, 256, 9, 256, 0);
  k_repack2<<<1152, 256, 0, stream>>>(INF(16), wrB,  128, 256, 9, 256, 128);
  k_repack2<<<576,  256, 0, stream>>>(INF(21), wrp1, 128, 128, 9, 128, 0);
  k_repack2<<<576,  256, 0, stream>>>(INF(22), wrp2, 128, 128, 9, 128, 0);
  k_repack2<<<1152, 256, 0, stream>>>(INF(23), wrpc, 256, 128, 9, 256, 0);
  k_repack2<<<256,  256, 0, stream>>>(INF(28), wrc1, 256, 256, 1, 256, 0);
  k_repack2<<<2304, 256, 0, stream>>>(INF(33), wrc2, 256, 256, 9, 256, 0);

  // 3) BN coefficients
  k_bncoef<<<1, 256, 0, stream>>>(INF(2),  INF(3),  INF(4),  INF(5),  scA,       shA,       128);
  k_bncoef<<<1, 256, 0, stream>>>(INF(7),  INF(8),  INF(9),  INF(10), scA + 128, shA + 128, 128);
  k_bncoef<<<1, 256, 0, stream>>>(INF(12), INF(13), INF(14), INF(15), scB,       shB,       128);
  k_bncoef<<<1, 256, 0, stream>>>(INF(17), INF(18), INF(19), INF(20), scB + 128, shB + 128, 128);
  k_bncoef<<<1, 256, 0, stream>>>(INF(24), INF(25), INF(26), INF(27), scp, shp, 256);
  k_bncoef<<<1, 256, 0, stream>>>(INF(29), INF(30), INF(31), INF(32), scb, shb, 256);
  k_bncoef<<<1, 256, 0, stream>>>(INF(34), INF(35), INF(36), INF(37), scc2, shc2, 256);

  // 4) bn1 = BN(conv1x1(x)) -> bnrel (hi/lo)
  k_conv<1><<<dim3(2048, 2), 256, 0, stream>>>(x_hl, 256, 512, wrc1, 256, scb, shb, nullptr, 0, 0, bnrel);
  // 5) yA = [look_conv1 | p1_conv1] (BN+ReLU) -> d_out scratch
  k_conv<9><<<dim3(2048, 2), 256, 0, stream>>>(x_hl, 256, 512, wrA, 256, scA, shA, nullptr, 1, 0, yscr);
  // 6) s1 = left_pool(look1) + p1_conv1 (in-place, ch [0:256))
  k_pool_s1<<<512, 256, 0, stream>>>(yscr);
  // 7) p1_look = conv(s1, p1lc) -> fp32
  k_conv<9><<<dim3(2048, 1), 256, 0, stream>>>(yscr, 128, 512, wrp1, 128, nullptr, nullptr, nullptr, 0, 1, p1lk);
  // 8) yB = [look_conv2 | p2_conv1] -> d_out scratch (x dead after)
  k_conv<9><<<dim3(2048, 2), 256, 0, stream>>>(x_hl, 256, 512, wrB, 256, scB, shB, nullptr, 1, 0, yscr);
  // 9) s2 = top_pool(look2) + p2_conv1 (in-place)
  k_pool_s2<<<512, 256, 0, stream>>>(yscr);
  // 10) p2_look = conv(s2, p2lc) -> fp32 (over dead x_hl)
  k_conv<9><<<dim3(2048, 1), 256, 0, stream>>>(yscr, 128, 512, wrp2, 128, nullptr, nullptr, nullptr, 0, 1, p2lk);
  // 11) ptmp = top_pool(p1_look) in-place
  k_tpool_f<<<512, 256, 0, stream>>>(p1lk);
  // 12) psum = left_pool(p2_look) + ptmp -> hi/lo compact
  k_lpool_add_f<<<512, 256, 0, stream>>>(p2lk, p1lk, psum);
  // 13) relu1 = relu(BN(conv(psum, pconv1)) + bn1) in-place over bn1
  k_conv<9><<<dim3(2048, 2), 256, 0, stream>>>(psum, 128, 256, wrpc, 256, scp, shp, bnrel, 1, 0, bnrel);
  // 14) out = relu(BN(conv(relu1, c2))) -> NCHW fp32 d_out
  k_conv<9><<<dim3(2048, 2), 256, 0, stream>>>(bnrel, 256, 512, wrc2, 256, scc2, shc2, nullptr, 1, 2, (float*)d_out);
#undef INF
}